// Round 1
// baseline (186.100 us; speedup 1.0000x reference)
//
#include <hip/hip_runtime.h>

// Polyphase 2x upsample + 23-tap CDF interpolation filter (separable, circular).
// Key fact: kernel taps at even offsets are 0 except center (=1.0), so the
// conv of the zero-stuffed upsample is polyphase:
//   out aligned with input grid (parity OFF): copy * k[11]
//   out misaligned: sum_{m=0..5} k[12+2m] * (in[base-m] + in[base+1+m])

#define TILE_OUT 64
#define TILE_IN  32
#define HALO     6
#define PATCH    (TILE_IN + 2 * HALO)   // 44
#define PATCH_S  (PATCH + 1)            // 45, LDS pad

template <int OFF>
__global__ __launch_bounds__(256) void upsample2_poly(
    const float* __restrict__ in, const float* __restrict__ kern,
    float* __restrict__ out, int H, int W) {
    __shared__ float sIn[PATCH][PATCH_S];
    __shared__ float sFh[PATCH][TILE_OUT];

    const int tid = threadIdx.x;
    const int tileX = blockIdx.x, tileY = blockIdx.y, ch = blockIdx.z;
    const int J0 = tileX * TILE_IN;   // input col origin of tile
    const int I0 = tileY * TILE_IN;   // input row origin
    const int W2 = 2 * W;

    // interpolation taps (broadcast scalar loads, L2-resident)
    const float k11 = kern[11];
    float c[6];
#pragma unroll
    for (int m = 0; m < 6; ++m) c[m] = kern[12 + 2 * m];

    const float* inC = in + (size_t)ch * H * W;

    // ---- Step 1: load 44x44 input patch with circular wrap ----
    for (int idx = tid; idx < PATCH * PATCH; idx += 256) {
        int r = idx / PATCH, cc = idx % PATCH;
        int gi = I0 - HALO + r;
        if (gi < 0) gi += H; else if (gi >= H) gi -= H;
        int gj = J0 - HALO + cc;
        if (gj < 0) gj += W; else if (gj >= W) gj -= W;
        sIn[r][cc] = inC[(size_t)gi * W + gj];
    }
    __syncthreads();

    // ---- Step 2: horizontal polyphase: sFh[r][x], x in [0,64) ----
    for (int idx = tid; idx < PATCH * TILE_OUT; idx += 256) {
        int r = idx >> 6, x = idx & 63;
        int xo = x - OFF;             // parity vs input grid (global X0 = 2*J0, even)
        float v;
        if ((xo & 1) == 0) {
            int l = HALO + (xo >> 1);
            v = k11 * sIn[r][l];
        } else {
            int lb = HALO + ((xo - 1) >> 1);   // arithmetic shift: xo-1 = -2 -> -1
            v = 0.f;
#pragma unroll
            for (int m = 0; m < 6; ++m)
                v += c[m] * (sIn[r][lb - m] + sIn[r][lb + 1 + m]);
        }
        sFh[r][x] = v;
    }
    __syncthreads();

    // ---- Step 3: vertical polyphase -> 64x64 output tile ----
    float* outC = out + (size_t)ch * (size_t)(2 * H) * W2;
    const int Y0 = 2 * I0, X0 = 2 * J0;
    for (int idx = tid; idx < TILE_OUT * TILE_OUT; idx += 256) {
        int y = idx >> 6, x = idx & 63;
        int yo = y - OFF;
        float v;
        if ((yo & 1) == 0) {
            int l = HALO + (yo >> 1);
            v = k11 * sFh[l][x];
        } else {
            int lb = HALO + ((yo - 1) >> 1);
            v = 0.f;
#pragma unroll
            for (int m = 0; m < 6; ++m)
                v += c[m] * (sFh[lb - m][x] + sFh[lb + 1 + m][x]);
        }
        outC[(size_t)(Y0 + y) * W2 + (X0 + x)] = v;
    }
}

extern "C" void kernel_launch(void* const* d_in, const int* in_sizes, int n_in,
                              void* d_out, int out_size, void* d_ws, size_t ws_size,
                              hipStream_t stream) {
    const float* x    = (const float*)d_in[0];   // (4,8,256,256) = (32,256,256)
    const float* kern = (const float*)d_in[1];   // 23 taps
    float* out = (float*)d_out;                  // (32,1024,1024)
    float* ws  = (float*)d_ws;                   // needs 32 MiB for (32,512,512)

    dim3 blk(256);
    // Stage 0: 256x256 -> 512x512, offset 1
    dim3 g0(256 / TILE_IN, 256 / TILE_IN, 32);
    upsample2_poly<1><<<g0, blk, 0, stream>>>(x, kern, ws, 256, 256);
    // Stage 1: 512x512 -> 1024x1024, offset 0
    dim3 g1(512 / TILE_IN, 512 / TILE_IN, 32);
    upsample2_poly<0><<<g1, blk, 0, stream>>>(ws, kern, out, 512, 512);
}